// Round 2
// baseline (304.324 us; speedup 1.0000x reference)
//
#include <hip/hip_runtime.h>

typedef short bf16x8 __attribute__((ext_vector_type(8)));
typedef float f32x4 __attribute__((ext_vector_type(4)));
typedef float f32x16 __attribute__((ext_vector_type(16)));

#define NSEQ 4096
#define BATCH 2
#define DIM 512
#define HEADS 8
#define NROWS (BATCH * NSEQ)   // 8192
#define QKVN (3 * DIM)         // 1536

__device__ __forceinline__ unsigned short f2bf(float f) {
  unsigned int u = __float_as_uint(f);
  u += 0x7fffu + ((u >> 16) & 1u);
  return (unsigned short)(u >> 16);
}
__device__ __forceinline__ float bf2f(unsigned short h) {
  return __uint_as_float(((unsigned int)h) << 16);
}
__device__ __forceinline__ void gload16(const unsigned short* g, unsigned short* l) {
  __builtin_amdgcn_global_load_lds((const __attribute__((address_space(1))) unsigned int*)g,
                                   (__attribute__((address_space(3))) unsigned int*)l, 16, 0, 0);
}

// ---------------- cos/sin tables ----------------
__global__ __launch_bounds__(256) void k_tables(const float* __restrict__ rot,
                                                float* __restrict__ cosT,
                                                float* __restrict__ sinT) {
  int i = blockIdx.x * 256 + threadIdx.x;
  float f = rot[i];
  cosT[i] = cosf(f);
  sinT[i] = sinf(f);
}

// ---------------- fp32 -> bf16 weight convert ----------------
__global__ __launch_bounds__(256) void k_cvt(const float* __restrict__ src,
                                             unsigned short* __restrict__ dst, int n) {
  int i = blockIdx.x * 256 + threadIdx.x;
  if (i < n) dst[i] = f2bf(src[i]);
}

// ---------------- LayerNorm: one wave per row ----------------
__global__ __launch_bounds__(256) void k_ln(const float* __restrict__ x,
                                            const float* __restrict__ w,
                                            const float* __restrict__ bb,
                                            unsigned short* __restrict__ xn) {
  int row = blockIdx.x * 4 + (threadIdx.x >> 6);
  int lane = threadIdx.x & 63;
  const float* xr = x + (size_t)row * DIM;
  float v[8];
  float s = 0.f;
#pragma unroll
  for (int j = 0; j < 8; ++j) { v[j] = xr[lane + j * 64]; s += v[j]; }
#pragma unroll
  for (int m = 1; m < 64; m <<= 1) s += __shfl_xor(s, m);
  float mu = s * (1.0f / DIM);
  float q = 0.f;
#pragma unroll
  for (int j = 0; j < 8; ++j) { float d = v[j] - mu; q += d * d; }
#pragma unroll
  for (int m = 1; m < 64; m <<= 1) q += __shfl_xor(q, m);
  float rs = rsqrtf(q * (1.0f / DIM) + 1e-5f);
#pragma unroll
  for (int j = 0; j < 8; ++j) {
    int col = lane + j * 64;
    xn[(size_t)row * DIM + col] = f2bf((v[j] - mu) * rs * w[col] + bb[col]);
  }
}

// ---------------- GEMM: C[M][N] = A[M][K] * B[N][K]^T  (m97-style) ----------------
template <int EPI>
__global__ __launch_bounds__(256) void k_gemm(const unsigned short* __restrict__ A,
                                              const unsigned short* __restrict__ B,
                                              void* __restrict__ C,
                                              const float* __restrict__ bias,
                                              int M, int N, int K) {
  __shared__ __align__(16) unsigned short As[128 * 32];
  __shared__ __align__(16) unsigned short Bs[128 * 32];
  int bm = blockIdx.x, bn = blockIdx.y;
  int tid = threadIdx.x;
  int lane = tid & 63, w = tid >> 6;
  int wm = (w >> 1) << 6, wn = (w & 1) << 6;
  f32x4 acc[4][4] = {};
  for (int kt = 0; kt < K; kt += 32) {
    __syncthreads();
#pragma unroll
    for (int i = 0; i < 2; ++i) {
      int c = tid + (i << 8);
      int row = c >> 2, kc = (c & 3) << 3;
      gload16(A + (size_t)(bm * 128 + row) * K + kt + kc, &As[(w * 64 + i * 256) * 8]);
      gload16(B + (size_t)(bn * 128 + row) * K + kt + kc, &Bs[(w * 64 + i * 256) * 8]);
    }
    __syncthreads();
    bf16x8 af[4], bfr[4];
#pragma unroll
    for (int mi = 0; mi < 4; ++mi)
      af[mi] = *(const bf16x8*)&As[(wm + mi * 16 + (lane & 15)) * 32 + ((lane >> 4) << 3)];
#pragma unroll
    for (int ni = 0; ni < 4; ++ni)
      bfr[ni] = *(const bf16x8*)&Bs[(wn + ni * 16 + (lane & 15)) * 32 + ((lane >> 4) << 3)];
#pragma unroll
    for (int mi = 0; mi < 4; ++mi)
#pragma unroll
      for (int ni = 0; ni < 4; ++ni)
        acc[mi][ni] = __builtin_amdgcn_mfma_f32_16x16x32_bf16(af[mi], bfr[ni], acc[mi][ni], 0, 0, 0);
  }
#pragma unroll
  for (int mi = 0; mi < 4; ++mi) {
#pragma unroll
    for (int ni = 0; ni < 4; ++ni) {
#pragma unroll
      for (int r = 0; r < 4; ++r) {
        int gm = bm * 128 + wm + mi * 16 + ((lane >> 4) << 2) + r;
        int gn = bn * 128 + wn + ni * 16 + (lane & 15);
        if (EPI == 0) {
          ((unsigned short*)C)[(size_t)gm * N + gn] = f2bf(acc[mi][ni][r]);
        } else {
          ((float*)C)[(size_t)gm * N + gn] = acc[mi][ni][r] + bias[gn];
        }
      }
    }
  }
}

// ---------------- RoPE + head split (+ V transpose); Q pre-scaled by 1/8 ----------------
__global__ __launch_bounds__(256) void k_rope_split(const unsigned short* __restrict__ qkv,
                                                    const float* __restrict__ cosT,
                                                    const float* __restrict__ sinT,
                                                    unsigned short* __restrict__ qh,
                                                    unsigned short* __restrict__ kh,
                                                    unsigned short* __restrict__ vt) {
  __shared__ unsigned short vs[128][65];
  int nt = blockIdx.x, bh = blockIdx.y;
  int b = bh >> 3, h = bh & 7;
  int n0 = nt * 128;
  int t = threadIdx.x;
  int sub = t >> 3, cc = t & 7;
#pragma unroll
  for (int rr = 0; rr < 4; ++rr) {
    int row = rr * 32 + sub;
    int n = n0 + row;
    size_t base = ((size_t)(b * NSEQ + n)) * QKVN + h * 64 + cc * 8;
    const float* cb = cosT + ((size_t)(b * NSEQ + n)) * 64 + cc * 8;
    const float* sb = sinT + ((size_t)(b * NSEQ + n)) * 64 + cc * 8;
    float c[8], sn[8];
#pragma unroll
    for (int j = 0; j < 8; ++j) { c[j] = cb[j]; sn[j] = sb[j]; }
    bf16x8 qv = *(const bf16x8*)(qkv + base);
    bf16x8 kv = *(const bf16x8*)(qkv + base + 512);
    bf16x8 vv = *(const bf16x8*)(qkv + base + 1024);
    union { bf16x8 v; unsigned short u[8]; } yq, yk;
#pragma unroll
    for (int j = 0; j < 8; j += 2) {
      {
        float e = bf2f((unsigned short)qv[j]), o = bf2f((unsigned short)qv[j + 1]);
        yq.u[j]     = f2bf((e * c[j] - o * sn[j]) * 0.125f);
        yq.u[j + 1] = f2bf((o * c[j + 1] + e * sn[j + 1]) * 0.125f);
      }
      {
        float e = bf2f((unsigned short)kv[j]), o = bf2f((unsigned short)kv[j + 1]);
        yk.u[j]     = f2bf(e * c[j] - o * sn[j]);
        yk.u[j + 1] = f2bf(o * c[j + 1] + e * sn[j + 1]);
      }
      {
        float e = bf2f((unsigned short)vv[j]), o = bf2f((unsigned short)vv[j + 1]);
        vs[row][cc * 8 + j]     = f2bf(e * c[j] - o * sn[j]);
        vs[row][cc * 8 + j + 1] = f2bf(o * c[j + 1] + e * sn[j + 1]);
      }
    }
    *(bf16x8*)(qh + ((size_t)bh * NSEQ + n) * 64 + cc * 8) = yq.v;
    *(bf16x8*)(kh + ((size_t)bh * NSEQ + n) * 64 + cc * 8) = yk.v;
  }
  __syncthreads();
  int d = t >> 2, c4 = t & 3;
#pragma unroll
  for (int g = 0; g < 4; ++g) {
    union { bf16x8 v; unsigned short u[8]; } tv;
#pragma unroll
    for (int j = 0; j < 8; ++j) tv.u[j] = vs[c4 * 32 + g * 8 + j][d];
    *(bf16x8*)(vt + ((size_t)bh * 64 + d) * NSEQ + n0 + c4 * 32 + g * 8) = tv.v;
  }
}

// ---------------- Flash attention v2: swapped-MFMA, lane-local softmax, no LDS ----------------
// 512 blocks x 4 independent waves; wave owns 32 q-rows; KV tile = 64 keys.
// S^T = mfma(K,Q): lane holds S[q=lane&31][k-local (r&3)+8*(r>>2)+4*hi, kb*32]
// O^T = mfma(VT,P): acc col = q = lane&31  -> softmax state fully lane-local.
__global__ __launch_bounds__(256, 2) void k_attn(const unsigned short* __restrict__ Qh,
                                                 const unsigned short* __restrict__ Kh,
                                                 const unsigned short* __restrict__ VT,
                                                 const float* __restrict__ cosT,
                                                 const float* __restrict__ sinT,
                                                 unsigned short* __restrict__ AO) {
  int bid = blockIdx.x;
  int i = bid >> 3;
  int bh = (bid & 7) + ((i >> 5) << 3);  // XCD-pinned: bh%8 == bid%8
  int qt = i & 31;
  int w = threadIdx.x >> 6, lane = threadIdx.x & 63;
  int lq = lane & 31, hi = lane >> 5;
  int q0 = qt * 128 + w * 32;
  int b = bh >> 3, h = bh & 7;

  const unsigned short* Qb = Qh + ((size_t)bh * NSEQ + q0 + lq) * 64 + hi * 8;
  bf16x8 qf[4];
#pragma unroll
  for (int j = 0; j < 4; ++j) qf[j] = *(const bf16x8*)(Qb + j * 16);

  const unsigned short* kp = Kh + ((size_t)bh * NSEQ + lq) * 64 + hi * 8;
  const unsigned short* vp = VT + ((size_t)bh * 64 + lq) * NSEQ + hi * 8;

  f32x16 acc0 = {}, acc1 = {};
  float m_run = -1e30f, l_run = 0.f;

#pragma unroll 1
  for (int k0 = 0; k0 < NSEQ; k0 += 64) {
    const unsigned short* kt = kp + (size_t)k0 * 64;
    bf16x8 kf0[4], kf1[4], vf0[4], vf1[4];
#pragma unroll
    for (int j = 0; j < 4; ++j) {
      kf0[j] = *(const bf16x8*)(kt + j * 16);
      kf1[j] = *(const bf16x8*)(kt + 2048 + j * 16);
    }
#pragma unroll
    for (int s = 0; s < 4; ++s) {
      vf0[s] = *(const bf16x8*)(vp + k0 + s * 16);
      vf1[s] = *(const bf16x8*)(vp + 32 * NSEQ + k0 + s * 16);
    }
    f32x16 s0 = {}, s1 = {};
#pragma unroll
    for (int j = 0; j < 4; ++j) {
      s0 = __builtin_amdgcn_mfma_f32_32x32x16_bf16(kf0[j], qf[j], s0, 0, 0, 0);
      s1 = __builtin_amdgcn_mfma_f32_32x32x16_bf16(kf1[j], qf[j], s1, 0, 0, 0);
    }
    // row max: 31 lane-local fmax + one half-swap
    float pm = s0[0];
#pragma unroll
    for (int r = 1; r < 16; ++r) pm = fmaxf(pm, s0[r]);
#pragma unroll
    for (int r = 0; r < 16; ++r) pm = fmaxf(pm, s1[r]);
    pm = fmaxf(pm, __shfl_xor(pm, 32));
    // defer-max (T13): skip O-rescale while growth <= 8
    if (!__all(pm <= m_run + 8.0f)) {
      float mn = fmaxf(m_run, pm);
      float corr = __expf(m_run - mn);
      l_run *= corr;
#pragma unroll
      for (int r = 0; r < 16; ++r) { acc0[r] *= corr; acc1[r] *= corr; }
      m_run = mn;
    }
    float p0[16], p1[16];
    float ls = 0.f;
#pragma unroll
    for (int r = 0; r < 16; ++r) { p0[r] = __expf(s0[r] - m_run); ls += p0[r]; }
#pragma unroll
    for (int r = 0; r < 16; ++r) { p1[r] = __expf(s1[r] - m_run); ls += p1[r]; }
    l_run += ls;  // per-half partial; halves summed once in epilogue
    // pack to bf16 (T12) + half-exchange
    unsigned int dw[2][4][2], xw[2][4][2];
#pragma unroll
    for (int rg = 0; rg < 4; ++rg) {
      asm("v_cvt_pk_bf16_f32 %0, %1, %2" : "=v"(dw[0][rg][0]) : "v"(p0[4 * rg + 0]), "v"(p0[4 * rg + 1]));
      asm("v_cvt_pk_bf16_f32 %0, %1, %2" : "=v"(dw[0][rg][1]) : "v"(p0[4 * rg + 2]), "v"(p0[4 * rg + 3]));
      asm("v_cvt_pk_bf16_f32 %0, %1, %2" : "=v"(dw[1][rg][0]) : "v"(p1[4 * rg + 0]), "v"(p1[4 * rg + 1]));
      asm("v_cvt_pk_bf16_f32 %0, %1, %2" : "=v"(dw[1][rg][1]) : "v"(p1[4 * rg + 2]), "v"(p1[4 * rg + 3]));
    }
#pragma unroll
    for (int kb = 0; kb < 2; ++kb)
#pragma unroll
      for (int rg = 0; rg < 4; ++rg) {
        xw[kb][rg][0] = __shfl_xor((int)dw[kb][rg][0], 32);
        xw[kb][rg][1] = __shfl_xor((int)dw[kb][rg][1], 32);
      }
#pragma unroll
    for (int sg = 0; sg < 4; ++sg) {
      int kb = sg >> 1;
      int rgx = ((sg & 1) << 1) + hi;
      union { unsigned int d[4]; bf16x8 v; } u;
      if (hi) {
        u.d[0] = xw[kb][rgx][0]; u.d[1] = xw[kb][rgx][1];
        u.d[2] = dw[kb][rgx][0]; u.d[3] = dw[kb][rgx][1];
      } else {
        u.d[0] = dw[kb][rgx][0]; u.d[1] = dw[kb][rgx][1];
        u.d[2] = xw[kb][rgx][0]; u.d[3] = xw[kb][rgx][1];
      }
      acc0 = __builtin_amdgcn_mfma_f32_32x32x16_bf16(vf0[sg], u.v, acc0, 0, 0, 0);
      acc1 = __builtin_amdgcn_mfma_f32_32x32x16_bf16(vf1[sg], u.v, acc1, 0, 0, 0);
    }
  }
  // epilogue: normalize + inverse RoPE (pairs adjacent in regs) + 8B stores
  float lfull = l_run + __shfl_xor(l_run, 32);
  float inv = 1.0f / lfull;
  int q = q0 + lq;
  const float* cb = cosT + ((size_t)b * NSEQ + q) * 64;
  const float* sb = sinT + ((size_t)b * NSEQ + q) * 64;
  unsigned short* ob = AO + ((size_t)(b * NSEQ + q)) * DIM + h * 64;
#pragma unroll
  for (int db = 0; db < 2; ++db) {
#pragma unroll
    for (int rg = 0; rg < 4; ++rg) {
      int dbase = db * 32 + 8 * rg + 4 * hi;
      float4 c4 = *(const float4*)(cb + dbase);
      float4 s4 = *(const float4*)(sb + dbase);
      float e0 = (db ? acc1[4 * rg + 0] : acc0[4 * rg + 0]) * inv;
      float o1 = (db ? acc1[4 * rg + 1] : acc0[4 * rg + 1]) * inv;
      float e2 = (db ? acc1[4 * rg + 2] : acc0[4 * rg + 2]) * inv;
      float o3 = (db ? acc1[4 * rg + 3] : acc0[4 * rg + 3]) * inv;
      float y0 = e0 * c4.x + o1 * s4.x;
      float y1 = o1 * c4.y - e0 * s4.y;
      float y2 = e2 * c4.z + o3 * s4.z;
      float y3 = o3 * c4.w - e2 * s4.w;
      unsigned int w0, w1;
      asm("v_cvt_pk_bf16_f32 %0, %1, %2" : "=v"(w0) : "v"(y0), "v"(y1));
      asm("v_cvt_pk_bf16_f32 %0, %1, %2" : "=v"(w1) : "v"(y2), "v"(y3));
      unsigned int uu[2] = {w0, w1};
      *(uint2*)(ob + dbase) = *(uint2*)uu;
    }
  }
}

extern "C" void kernel_launch(void* const* d_in, const int* in_sizes, int n_in,
                              void* d_out, int out_size, void* d_ws, size_t ws_size,
                              hipStream_t stream) {
  const float* x    = (const float*)d_in[0];
  const float* rot  = (const float*)d_in[1];
  const float* lnw  = (const float*)d_in[2];
  const float* lnb  = (const float*)d_in[3];
  const float* wqkv = (const float*)d_in[4];
  const float* wout = (const float*)d_in[5];
  const float* bout = (const float*)d_in[6];
  float* out = (float*)d_out;

  char* ws = (char*)d_ws;
  const size_t MB = (size_t)1 << 20;
  float* cosT          = (float*)(ws + 0 * MB);
  float* sinT          = (float*)(ws + 2 * MB);
  unsigned short* wqkb = (unsigned short*)(ws + 4 * MB);
  unsigned short* wob  = (unsigned short*)(ws + 6 * MB);
  unsigned short* xn   = (unsigned short*)(ws + 8 * MB);
  unsigned short* qkv  = (unsigned short*)(ws + 16 * MB);
  unsigned short* ao   = (unsigned short*)(ws + 16 * MB);  // reuse (qkv dead after split)
  unsigned short* qh   = (unsigned short*)(ws + 40 * MB);
  unsigned short* kh   = (unsigned short*)(ws + 48 * MB);
  unsigned short* vt   = (unsigned short*)(ws + 56 * MB);

  k_tables<<<(BATCH * NSEQ * 64) / 256, 256, 0, stream>>>(rot, cosT, sinT);
  k_cvt<<<(QKVN * DIM + 255) / 256, 256, 0, stream>>>(wqkv, wqkb, QKVN * DIM);
  k_cvt<<<(DIM * DIM + 255) / 256, 256, 0, stream>>>(wout, wob, DIM * DIM);
  k_ln<<<NROWS / 4, 256, 0, stream>>>(x, lnw, lnb, xn);
  k_gemm<0><<<dim3(NROWS / 128, QKVN / 128), 256, 0, stream>>>(xn, wqkb, qkv, nullptr,
                                                               NROWS, QKVN, DIM);
  k_rope_split<<<dim3(NSEQ / 128, 16), 256, 0, stream>>>(qkv, cosT, sinT, qh, kh, vt);
  k_attn<<<512, 256, 0, stream>>>(qh, kh, vt, cosT, sinT, ao);
  k_gemm<1><<<dim3(NROWS / 128, DIM / 128), 256, 0, stream>>>(ao, wob, out, bout,
                                                              NROWS, DIM, DIM);
}

// Round 4
// 186.683 us; speedup vs baseline: 1.6302x; 1.6302x over previous
//
#include <hip/hip_runtime.h>

typedef short bf16x8 __attribute__((ext_vector_type(8)));
typedef float f32x4 __attribute__((ext_vector_type(4)));
typedef float f32x16 __attribute__((ext_vector_type(16)));

#define NSEQ 4096
#define BATCH 2
#define DIM 512
#define HEADS 8
#define NROWS (BATCH * NSEQ)   // 8192
#define QKVN (3 * DIM)         // 1536

__device__ __forceinline__ unsigned short f2bf(float f) {
  unsigned int u = __float_as_uint(f);
  u += 0x7fffu + ((u >> 16) & 1u);
  return (unsigned short)(u >> 16);
}
__device__ __forceinline__ float bf2f(unsigned short h) {
  return __uint_as_float(((unsigned int)h) << 16);
}
__device__ __forceinline__ void gload16(const unsigned short* g, unsigned short* l) {
  __builtin_amdgcn_global_load_lds((const __attribute__((address_space(1))) unsigned int*)g,
                                   (__attribute__((address_space(3))) unsigned int*)l, 16, 0, 0);
}

// ---------------- cos/sin tables ----------------
__global__ __launch_bounds__(256) void k_tables(const float* __restrict__ rot,
                                                float* __restrict__ cosT,
                                                float* __restrict__ sinT) {
  int i = blockIdx.x * 256 + threadIdx.x;
  float f = rot[i];
  cosT[i] = cosf(f);
  sinT[i] = sinf(f);
}

// ---------------- fp32 -> bf16 weight convert ----------------
__global__ __launch_bounds__(256) void k_cvt(const float* __restrict__ src,
                                             unsigned short* __restrict__ dst, int n) {
  int i = blockIdx.x * 256 + threadIdx.x;
  if (i < n) dst[i] = f2bf(src[i]);
}

// ---------------- LayerNorm: one wave per row ----------------
__global__ __launch_bounds__(256) void k_ln(const float* __restrict__ x,
                                            const float* __restrict__ w,
                                            const float* __restrict__ bb,
                                            unsigned short* __restrict__ xn) {
  int row = blockIdx.x * 4 + (threadIdx.x >> 6);
  int lane = threadIdx.x & 63;
  const float* xr = x + (size_t)row * DIM;
  float v[8];
  float s = 0.f;
#pragma unroll
  for (int j = 0; j < 8; ++j) { v[j] = xr[lane + j * 64]; s += v[j]; }
#pragma unroll
  for (int m = 1; m < 64; m <<= 1) s += __shfl_xor(s, m);
  float mu = s * (1.0f / DIM);
  float q = 0.f;
#pragma unroll
  for (int j = 0; j < 8; ++j) { float d = v[j] - mu; q += d * d; }
#pragma unroll
  for (int m = 1; m < 64; m <<= 1) q += __shfl_xor(q, m);
  float rs = rsqrtf(q * (1.0f / DIM) + 1e-5f);
#pragma unroll
  for (int j = 0; j < 8; ++j) {
    int col = lane + j * 64;
    xn[(size_t)row * DIM + col] = f2bf((v[j] - mu) * rs * w[col] + bb[col]);
  }
}

// ---------------- GEMM: C[M][N] = A[M][K] * B[N][K]^T  (m97-style) ----------------
template <int EPI>
__global__ __launch_bounds__(256) void k_gemm(const unsigned short* __restrict__ A,
                                              const unsigned short* __restrict__ B,
                                              void* __restrict__ C,
                                              const float* __restrict__ bias,
                                              int M, int N, int K) {
  __shared__ __align__(16) unsigned short As[128 * 32];
  __shared__ __align__(16) unsigned short Bs[128 * 32];
  int bm = blockIdx.x, bn = blockIdx.y;
  int tid = threadIdx.x;
  int lane = tid & 63, w = tid >> 6;
  int wm = (w >> 1) << 6, wn = (w & 1) << 6;
  f32x4 acc[4][4] = {};
  for (int kt = 0; kt < K; kt += 32) {
    __syncthreads();
#pragma unroll
    for (int i = 0; i < 2; ++i) {
      int c = tid + (i << 8);
      int row = c >> 2, kc = (c & 3) << 3;
      gload16(A + (size_t)(bm * 128 + row) * K + kt + kc, &As[(w * 64 + i * 256) * 8]);
      gload16(B + (size_t)(bn * 128 + row) * K + kt + kc, &Bs[(w * 64 + i * 256) * 8]);
    }
    __syncthreads();
    bf16x8 af[4], bfr[4];
#pragma unroll
    for (int mi = 0; mi < 4; ++mi)
      af[mi] = *(const bf16x8*)&As[(wm + mi * 16 + (lane & 15)) * 32 + ((lane >> 4) << 3)];
#pragma unroll
    for (int ni = 0; ni < 4; ++ni)
      bfr[ni] = *(const bf16x8*)&Bs[(wn + ni * 16 + (lane & 15)) * 32 + ((lane >> 4) << 3)];
#pragma unroll
    for (int mi = 0; mi < 4; ++mi)
#pragma unroll
      for (int ni = 0; ni < 4; ++ni)
        acc[mi][ni] = __builtin_amdgcn_mfma_f32_16x16x32_bf16(af[mi], bfr[ni], acc[mi][ni], 0, 0, 0);
  }
#pragma unroll
  for (int mi = 0; mi < 4; ++mi) {
#pragma unroll
    for (int ni = 0; ni < 4; ++ni) {
#pragma unroll
      for (int r = 0; r < 4; ++r) {
        int gm = bm * 128 + wm + mi * 16 + ((lane >> 4) << 2) + r;
        int gn = bn * 128 + wn + ni * 16 + (lane & 15);
        if (EPI == 0) {
          ((unsigned short*)C)[(size_t)gm * N + gn] = f2bf(acc[mi][ni][r]);
        } else {
          ((float*)C)[(size_t)gm * N + gn] = acc[mi][ni][r] + bias[gn];
        }
      }
    }
  }
}

// ---------------- RoPE + head split (+ V transpose); Q pre-scaled by 1/8 ----------------
__global__ __launch_bounds__(256) void k_rope_split(const unsigned short* __restrict__ qkv,
                                                    const float* __restrict__ cosT,
                                                    const float* __restrict__ sinT,
                                                    unsigned short* __restrict__ qh,
                                                    unsigned short* __restrict__ kh,
                                                    unsigned short* __restrict__ vt) {
  __shared__ unsigned short vs[128][65];
  int nt = blockIdx.x, bh = blockIdx.y;
  int b = bh >> 3, h = bh & 7;
  int n0 = nt * 128;
  int t = threadIdx.x;
  int sub = t >> 3, cc = t & 7;
#pragma unroll
  for (int rr = 0; rr < 4; ++rr) {
    int row = rr * 32 + sub;
    int n = n0 + row;
    size_t base = ((size_t)(b * NSEQ + n)) * QKVN + h * 64 + cc * 8;
    const float* cb = cosT + ((size_t)(b * NSEQ + n)) * 64 + cc * 8;
    const float* sb = sinT + ((size_t)(b * NSEQ + n)) * 64 + cc * 8;
    float c[8], sn[8];
#pragma unroll
    for (int j = 0; j < 8; ++j) { c[j] = cb[j]; sn[j] = sb[j]; }
    bf16x8 qv = *(const bf16x8*)(qkv + base);
    bf16x8 kv = *(const bf16x8*)(qkv + base + 512);
    bf16x8 vv = *(const bf16x8*)(qkv + base + 1024);
    union { bf16x8 v; unsigned short u[8]; } yq, yk;
#pragma unroll
    for (int j = 0; j < 8; j += 2) {
      {
        float e = bf2f((unsigned short)qv[j]), o = bf2f((unsigned short)qv[j + 1]);
        yq.u[j]     = f2bf((e * c[j] - o * sn[j]) * 0.125f);
        yq.u[j + 1] = f2bf((o * c[j + 1] + e * sn[j + 1]) * 0.125f);
      }
      {
        float e = bf2f((unsigned short)kv[j]), o = bf2f((unsigned short)kv[j + 1]);
        yk.u[j]     = f2bf(e * c[j] - o * sn[j]);
        yk.u[j + 1] = f2bf(o * c[j + 1] + e * sn[j + 1]);
      }
      {
        float e = bf2f((unsigned short)vv[j]), o = bf2f((unsigned short)vv[j + 1]);
        vs[row][cc * 8 + j]     = f2bf(e * c[j] - o * sn[j]);
        vs[row][cc * 8 + j + 1] = f2bf(o * c[j + 1] + e * sn[j + 1]);
      }
    }
    *(bf16x8*)(qh + ((size_t)bh * NSEQ + n) * 64 + cc * 8) = yq.v;
    *(bf16x8*)(kh + ((size_t)bh * NSEQ + n) * 64 + cc * 8) = yk.v;
  }
  __syncthreads();
  int d = t >> 2, c4 = t & 3;
#pragma unroll
  for (int g = 0; g < 4; ++g) {
    union { bf16x8 v; unsigned short u[8]; } tv;
#pragma unroll
    for (int j = 0; j < 8; ++j) tv.u[j] = vs[c4 * 32 + g * 8 + j][d];
    *(bf16x8*)(vt + ((size_t)bh * 64 + d) * NSEQ + n0 + c4 * 32 + g * 8) = tv.v;
  }
}

// ---------------- Flash attention v4: LDS-shared K/V dbuf + proven shfl_xor exchange ----
// 512 blocks x 4 waves. Wave owns 32 q-rows; block shares KVBLK=64 tiles (K and V[d][k]) in LDS.
// Stage: global_load_lds w/ source-side XOR pre-swizzle (slot ^= row&7); reads apply same XOR.
// Softmax lane-local via swapped QK^T; P exchange via __shfl_xor(32) + static cndmask select
// (round-2-proven mapping, scratch-free).
__global__ __launch_bounds__(256, 2) void k_attn(const unsigned short* __restrict__ Qh,
                                                 const unsigned short* __restrict__ Kh,
                                                 const unsigned short* __restrict__ VT,
                                                 const float* __restrict__ cosT,
                                                 const float* __restrict__ sinT,
                                                 unsigned short* __restrict__ AO) {
  __shared__ __align__(16) unsigned short Ks[2][64 * 64];
  __shared__ __align__(16) unsigned short Vs[2][64 * 64];
  int bid = blockIdx.x;
  int bh = (bid & 7) + ((bid >> 8) << 3);   // XCD-pinned: bh%8 == bid%8
  int qt = (bid >> 3) & 31;
  int tid = threadIdx.x;
  int w = tid >> 6, lane = tid & 63;
  int lq = lane & 31, hi = lane >> 5;
  int q0 = qt * 128 + w * 32;
  int b = bh >> 3, h = bh & 7;

  const unsigned short* Kbh = Kh + (size_t)bh * NSEQ * 64;
  const unsigned short* Vbh = VT + (size_t)bh * 64 * NSEQ;

  // Q fragments (B-operand): Q[q0+lq][j*16 + hi*8 .. +8]
  const unsigned short* Qb = Qh + ((size_t)bh * NSEQ + q0 + lq) * 64 + hi * 8;
  bf16x8 qf[4];
#pragma unroll
  for (int j = 0; j < 4; ++j) qf[j] = *(const bf16x8*)(Qb + j * 16);

  // staging chunk geometry: chunk c -> row r=c>>3, source 16B slot (c&7)^(r&7)
  int c0 = w * 64 + lane;
  int r0 = c0 >> 3, sw0 = ((c0 & 7) ^ (r0 & 7)) << 3;
  int c1 = c0 + 256;
  int r1 = c1 >> 3, sw1 = ((c1 & 7) ^ (r1 & 7)) << 3;
  int ld0 = (w * 64) * 8, ld1 = (256 + w * 64) * 8;

  f32x16 acc0 = {}, acc1 = {};
  float m_run = -1e30f, l_run = 0.f;

  // prologue: stage tile 0 into buf 0
  gload16(Kbh + (size_t)r0 * 64 + sw0, &Ks[0][ld0]);
  gload16(Kbh + (size_t)r1 * 64 + sw1, &Ks[0][ld1]);
  gload16(Vbh + (size_t)r0 * NSEQ + sw0, &Vs[0][ld0]);
  gload16(Vbh + (size_t)r1 * NSEQ + sw1, &Vs[0][ld1]);
  __syncthreads();
  int cur = 0;
  int swz = (lq & 7) << 4;

  for (int k0 = 0; k0 < NSEQ; k0 += 64) {
    if (k0 + 64 < NSEQ) {
      int k1 = k0 + 64, nxt = cur ^ 1;
      gload16(Kbh + (size_t)(k1 + r0) * 64 + sw0, &Ks[nxt][ld0]);
      gload16(Kbh + (size_t)(k1 + r1) * 64 + sw1, &Ks[nxt][ld1]);
      gload16(Vbh + (size_t)r0 * NSEQ + k1 + sw0, &Vs[nxt][ld0]);
      gload16(Vbh + (size_t)r1 * NSEQ + k1 + sw1, &Vs[nxt][ld1]);
    }
    // ---- QK^T ----
    const char* kbase = (const char*)&Ks[cur][0];
    f32x16 s0 = {}, s1 = {};
    __builtin_amdgcn_s_setprio(1);
#pragma unroll
    for (int j = 0; j < 4; ++j) {
      int cb = j * 32 + hi * 16;
      bf16x8 a0 = *(const bf16x8*)(kbase + lq * 128 + (cb ^ swz));
      bf16x8 a1 = *(const bf16x8*)(kbase + (32 + lq) * 128 + (cb ^ swz));
      s0 = __builtin_amdgcn_mfma_f32_32x32x16_bf16(a0, qf[j], s0, 0, 0, 0);
      s1 = __builtin_amdgcn_mfma_f32_32x32x16_bf16(a1, qf[j], s1, 0, 0, 0);
    }
    __builtin_amdgcn_s_setprio(0);
    // ---- softmax (lane-local; one cross-half shfl) ----
    float mx[16];
#pragma unroll
    for (int r = 0; r < 16; ++r) mx[r] = fmaxf(s0[r], s1[r]);
#pragma unroll
    for (int st = 8; st >= 1; st >>= 1)
#pragma unroll
      for (int r = 0; r < 8; ++r)
        if (r < st) mx[r] = fmaxf(mx[r], mx[r + st]);
    float pm = fmaxf(mx[0], __shfl_xor(mx[0], 32));
    if (!__all(pm <= m_run + 8.0f)) {  // defer-max (T13)
      float mn = fmaxf(m_run, pm);
      float corr = __expf(m_run - mn);
      l_run *= corr;
#pragma unroll
      for (int r = 0; r < 16; ++r) { acc0[r] *= corr; acc1[r] *= corr; }
      m_run = mn;
    }
#pragma unroll
    for (int r = 0; r < 16; ++r) s0[r] = __expf(s0[r] - m_run);
#pragma unroll
    for (int r = 0; r < 16; ++r) s1[r] = __expf(s1[r] - m_run);
    // sum tree
    float ts[8];
#pragma unroll
    for (int m = 0; m < 8; ++m)
      ts[m] = (s0[2 * m] + s0[2 * m + 1]) + (s1[2 * m] + s1[2 * m + 1]);
#pragma unroll
    for (int m = 0; m < 4; ++m) ts[m] += ts[m + 4];
    l_run += (ts[0] + ts[1]) + (ts[2] + ts[3]);
    // ---- pack P -> bf16 (cvt_pk) + cross-half exchange (shfl_xor, round-2-proven) ----
    unsigned int dw[16], xw[16];
#pragma unroll
    for (int m = 0; m < 8; ++m) {
      asm("v_cvt_pk_bf16_f32 %0, %1, %2" : "=v"(dw[m]) : "v"(s0[2 * m]), "v"(s0[2 * m + 1]));
      asm("v_cvt_pk_bf16_f32 %0, %1, %2" : "=v"(dw[8 + m]) : "v"(s1[2 * m]), "v"(s1[2 * m + 1]));
    }
#pragma unroll
    for (int m = 0; m < 16; ++m) xw[m] = (unsigned int)__shfl_xor((int)dw[m], 32);
    // ---- PV ----
    const char* vbase = (const char*)&Vs[cur][0];
    __builtin_amdgcn_s_setprio(1);
#pragma unroll
    for (int kk = 0; kk < 4; ++kk) {
      const int B = 4 * kk;
      union { unsigned int d[4]; bf16x8 v; } pu;
      pu.d[0] = hi ? xw[B + 2] : dw[B + 0];
      pu.d[1] = hi ? xw[B + 3] : dw[B + 1];
      pu.d[2] = hi ? dw[B + 2] : xw[B + 0];
      pu.d[3] = hi ? dw[B + 3] : xw[B + 1];
      int cb = kk * 32 + hi * 16;
      bf16x8 v0 = *(const bf16x8*)(vbase + lq * 128 + (cb ^ swz));
      bf16x8 v1 = *(const bf16x8*)(vbase + (32 + lq) * 128 + (cb ^ swz));
      acc0 = __builtin_amdgcn_mfma_f32_32x32x16_bf16(v0, pu.v, acc0, 0, 0, 0);
      acc1 = __builtin_amdgcn_mfma_f32_32x32x16_bf16(v1, pu.v, acc1, 0, 0, 0);
    }
    __builtin_amdgcn_s_setprio(0);
    __syncthreads();
    cur ^= 1;
  }
  // ---- epilogue: normalize + inverse RoPE + 8B stores ----
  float inv = 1.0f / (l_run + __shfl_xor(l_run, 32));
  int q = q0 + lq;
  const float* cb = cosT + ((size_t)b * NSEQ + q) * 64;
  const float* sb = sinT + ((size_t)b * NSEQ + q) * 64;
  unsigned short* ob = AO + ((size_t)(b * NSEQ + q)) * DIM + h * 64;
#pragma unroll
  for (int dh = 0; dh < 2; ++dh) {
#pragma unroll
    for (int rg = 0; rg < 4; ++rg) {
      int dbase = dh * 32 + 8 * rg + 4 * hi;
      float4 c4 = *(const float4*)(cb + dbase);
      float4 s4 = *(const float4*)(sb + dbase);
      float e0 = (dh ? acc1[4 * rg + 0] : acc0[4 * rg + 0]) * inv;
      float o1 = (dh ? acc1[4 * rg + 1] : acc0[4 * rg + 1]) * inv;
      float e2 = (dh ? acc1[4 * rg + 2] : acc0[4 * rg + 2]) * inv;
      float o3 = (dh ? acc1[4 * rg + 3] : acc0[4 * rg + 3]) * inv;
      float y0 = e0 * c4.x + o1 * s4.x;
      float y1 = o1 * c4.y - e0 * s4.y;
      float y2 = e2 * c4.z + o3 * s4.z;
      float y3 = o3 * c4.w - e2 * s4.w;
      unsigned int w0, w1;
      asm("v_cvt_pk_bf16_f32 %0, %1, %2" : "=v"(w0) : "v"(y0), "v"(y1));
      asm("v_cvt_pk_bf16_f32 %0, %1, %2" : "=v"(w1) : "v"(y2), "v"(y3));
      unsigned int uu[2] = {w0, w1};
      *(uint2*)(ob + dbase) = *(uint2*)uu;
    }
  }
}

extern "C" void kernel_launch(void* const* d_in, const int* in_sizes, int n_in,
                              void* d_out, int out_size, void* d_ws, size_t ws_size,
                              hipStream_t stream) {
  const float* x    = (const float*)d_in[0];
  const float* rot  = (const float*)d_in[1];
  const float* lnw  = (const float*)d_in[2];
  const float* lnb  = (const float*)d_in[3];
  const float* wqkv = (const float*)d_in[4];
  const float* wout = (const float*)d_in[5];
  const float* bout = (const float*)d_in[6];
  float* out = (float*)d_out;

  char* ws = (char*)d_ws;
  const size_t MB = (size_t)1 << 20;
  float* cosT          = (float*)(ws + 0 * MB);
  float* sinT          = (float*)(ws + 2 * MB);
  unsigned short* wqkb = (unsigned short*)(ws + 4 * MB);
  unsigned short* wob  = (unsigned short*)(ws + 6 * MB);
  unsigned short* xn   = (unsigned short*)(ws + 8 * MB);
  unsigned short* qkv  = (unsigned short*)(ws + 16 * MB);
  unsigned short* ao   = (unsigned short*)(ws + 16 * MB);  // reuse (qkv dead after split)
  unsigned short* qh   = (unsigned short*)(ws + 40 * MB);
  unsigned short* kh   = (unsigned short*)(ws + 48 * MB);
  unsigned short* vt   = (unsigned short*)(ws + 56 * MB);

  k_tables<<<(BATCH * NSEQ * 64) / 256, 256, 0, stream>>>(rot, cosT, sinT);
  k_cvt<<<(QKVN * DIM + 255) / 256, 256, 0, stream>>>(wqkv, wqkb, QKVN * DIM);
  k_cvt<<<(DIM * DIM + 255) / 256, 256, 0, stream>>>(wout, wob, DIM * DIM);
  k_ln<<<NROWS / 4, 256, 0, stream>>>(x, lnw, lnb, xn);
  k_gemm<0><<<dim3(NROWS / 128, QKVN / 128), 256, 0, stream>>>(xn, wqkb, qkv, nullptr,
                                                               NROWS, QKVN, DIM);
  k_rope_split<<<dim3(NSEQ / 128, 16), 256, 0, stream>>>(qkv, cosT, sinT, qh, kh, vt);
  k_attn<<<512, 256, 0, stream>>>(qh, kh, vt, cosT, sinT, ao);
  k_gemm<1><<<dim3(NROWS / 128, DIM / 128), 256, 0, stream>>>(ao, wob, out, bout,
                                                              NROWS, DIM, DIM);
}